// Round 21
// baseline (41.042 us; speedup 1.0000x reference)
//
#include <hip/hip_runtime.h>
#include <hip/hip_bf16.h>

// out[b,v] = dot(OT[b, pid[v], :], W[v, :]) + bias[v]
// B=32, Q=180, H=768, V=19004. fp32 in/out, bf16 MFMA inside.
#define BB 32
#define QQ 180
#define HH 768
#define VV 19004
#define VB 64
#define SB 19008     // res stride (pos dim)
#define MAXDESC 480
#define ST 776       // OT LDS row stride in bf16 elems (768 + 8 pad)
#define NB 80        // prep blocks
#define CH 238       // v's per prep block (80*238 = 19040 >= VV)

// ws layout (bytes)
#define WS_H      0        // NB*QQ ints = 57600
#define WS_NTOT   65536    // 1 int
#define WS_DESC   66560    // MAXDESC int4 = 7680
#define WS_SORTED 74752    // VV ints = 76016
#define WS_POSOF  151552   // VV ints = 76016
#define WS_RES    229376   // 32 * 19008 * 4 = 2,433,024

typedef __attribute__((ext_vector_type(8))) short short8v;  // 8 bf16 (4 VGPR)
typedef __attribute__((ext_vector_type(4))) float f32x4;

__device__ __forceinline__ unsigned pk2(float lo, float hi) {  // 2xbf16 RNE, packed
    __hip_bfloat162 r = __float22bfloat162_rn(make_float2(lo, hi));
    unsigned u;
    __builtin_memcpy(&u, &r, 4);
    return u;
}

// ---------- prep 1: per-block LDS histograms (R16 verbatim) ----------
__global__ void hist_k(const int* __restrict__ pid, int* __restrict__ h) {
    __shared__ int lc[QQ];
    const int t = threadIdx.x, b = blockIdx.x;
    if (t < QQ) lc[t] = 0;
    __syncthreads();
    const int v = b * CH + t;
    if (t < CH && v < VV) atomicAdd(&lc[pid[v]], 1);
    __syncthreads();
    if (t < QQ) h[b * QQ + t] = lc[t];
}

// ---------- prep 2: local scan + scatter; block 0 emits desc/ntot (R16) ------
__global__ void scat_k(const int* __restrict__ pid, const int* __restrict__ h,
                       int* __restrict__ sorted, int* __restrict__ posOf,
                       int4* __restrict__ desc, int* __restrict__ ntot) {
    __shared__ int s1[256];
    __shared__ int s2[256];
    __shared__ int cur[QQ];
    const int t = threadIdx.x, b = blockIdx.x;
    int c = 0, mybase = 0;
    if (t < QQ) {
        for (int i = 0; i < NB; ++i) {       // column sum + prefix before b
            if (i == b) mybase = c;
            c += h[i * QQ + t];
        }
    }
    s1[t] = c;
    __syncthreads();
    for (int off = 1; off < 256; off <<= 1) {
        int a = (t >= off) ? s1[t - off] : 0;
        __syncthreads();
        s1[t] += a;
        __syncthreads();
    }
    const int qs = s1[t] - c;                // exclusive prefix over q
    if (t < QQ) cur[t] = qs + mybase;
    if (b == 0) {                            // desc + ntot (uniform branch)
        const int nch = (c + VB - 1) / VB;
        s2[t] = nch;
        __syncthreads();
        for (int off = 1; off < 256; off <<= 1) {
            int a = (t >= off) ? s2[t - off] : 0;
            __syncthreads();
            s2[t] += a;
            __syncthreads();
        }
        if (t < QQ) {
            const int cb = s2[t] - nch;
            for (int j = 0; j < nch; ++j)
                desc[cb + j] = make_int4(t, qs + j * VB, min(VB, c - j * VB), 0);
        }
        if (t == 255) *ntot = s2[255];
    }
    __syncthreads();
    const int v = b * CH + t;
    if (t < CH && v < VV) {
        const int q = pid[v];
        const int pos = atomicAdd(&cur[q], 1);   // LDS cursors, 1 block
        sorted[pos] = v;
        posOf[v] = pos;
    }
}

// ---------- main: MFMA 16x16x32 bf16, block = chunk, full K=768 ----------
// 374 active blocks. OT[32][768] staged once as bf16 (48.5 KB LDS). W in a
// 12+12 float4 DOUBLE BUFFER (peak 96 VGPR of W data, 12-24 loads always in
// flight): issue wa(0..5), barrier, issue wb(6..11), compute wa, issue
// wa(12..17), compute wb, issue wb(18..23), compute, compute. Single res
// plane, full-line pos-space stores.
#define MSTEP(kk, F0, F1)                                                     \
    {                                                                         \
        int4 p_;                                                              \
        p_.x = (int)pk2((F0).x, (F0).y); p_.y = (int)pk2((F0).z, (F0).w);     \
        p_.z = (int)pk2((F1).x, (F1).y); p_.w = (int)pk2((F1).z, (F1).w);     \
        short8v bf_;                                                          \
        __builtin_memcpy(&bf_, &p_, 16);                                      \
        const short8v a0v_ = *(const short8v*)(a0p + (kk) * 32);              \
        const short8v a1v_ = *(const short8v*)(a0p + 16 * ST + (kk) * 32);    \
        acc0 = __builtin_amdgcn_mfma_f32_16x16x32_bf16(a0v_, bf_, acc0, 0, 0, 0); \
        acc1 = __builtin_amdgcn_mfma_f32_16x16x32_bf16(a1v_, bf_, acc1, 0, 0, 0); \
    }

__launch_bounds__(256)
__global__ void main_k(const float* __restrict__ OT, const float* __restrict__ W,
                       const int* __restrict__ sorted, const int4* __restrict__ desc,
                       const int* __restrict__ ntot, float* __restrict__ res) {
    const int nt = *ntot;
    const int ci = blockIdx.x;
    if (ci >= nt) return;
    const int4 d = desc[ci];
    const int q     = __builtin_amdgcn_readfirstlane(d.x);
    const int start = __builtin_amdgcn_readfirstlane(d.y);
    const int len   = __builtin_amdgcn_readfirstlane(d.z);
    const int tid = threadIdx.x;

    __shared__ short OTlds[BB * ST];  // 49,664 B

    const int lane = tid & 63;
    const int w = tid >> 6;           // v-tile
    const int co = lane & 15;         // frag col
    const int kq = lane >> 4;         // k-quad
    const int vl = 16 * w + co;       // v-local in chunk
    const int vg = sorted[start + min(vl, len - 1)];
    const float4* wp4 = (const float4*)(W + (size_t)vg * HH + kq * 8);

    // buffer A: K-steps 0..5 — issued FIRST so W loads overlap OT staging
    float4 wa[12], wb[12];
#pragma unroll
    for (int j = 0; j < 6; ++j) {
        wa[2 * j]     = wp4[j * 8];
        wa[2 * j + 1] = wp4[j * 8 + 1];
    }

    // stage OT[0..31][q][0..768) as bf16 (coalesced fp32 reads, packed cvt)
    {
        const int r = tid >> 3;   // b row 0..31
        const int o = tid & 7;    // octet
        const float* src = OT + ((size_t)r * QQ + q) * HH + o * 8;
        short* dst = &OTlds[r * ST + o * 8];
#pragma unroll
        for (int it = 0; it < 12; ++it) {
            const float4 f0 = *(const float4*)(src + it * 64);
            const float4 f1 = *(const float4*)(src + it * 64 + 4);
            int4 p;
            p.x = (int)pk2(f0.x, f0.y); p.y = (int)pk2(f0.z, f0.w);
            p.z = (int)pk2(f1.x, f1.y); p.w = (int)pk2(f1.z, f1.w);
            *(int4*)(dst + it * 64) = p;
        }
    }

    __syncthreads();

    const short* a0p = &OTlds[co * ST + kq * 8];
    f32x4 acc0 = {0.f, 0.f, 0.f, 0.f};
    f32x4 acc1 = {0.f, 0.f, 0.f, 0.f};

    // issue B: steps 6..11
#pragma unroll
    for (int j = 0; j < 6; ++j) {
        wb[2 * j]     = wp4[(6 + j) * 8];
        wb[2 * j + 1] = wp4[(6 + j) * 8 + 1];
    }
    // compute steps 0..5 from A
#pragma unroll
    for (int kk = 0; kk < 6; ++kk) MSTEP(kk, wa[2 * kk], wa[2 * kk + 1]);
    // re-issue A: steps 12..17
#pragma unroll
    for (int j = 0; j < 6; ++j) {
        wa[2 * j]     = wp4[(12 + j) * 8];
        wa[2 * j + 1] = wp4[(12 + j) * 8 + 1];
    }
    // compute steps 6..11 from B
#pragma unroll
    for (int kk = 0; kk < 6; ++kk) MSTEP(6 + kk, wb[2 * kk], wb[2 * kk + 1]);
    // re-issue B: steps 18..23
#pragma unroll
    for (int j = 0; j < 6; ++j) {
        wb[2 * j]     = wp4[(18 + j) * 8];
        wb[2 * j + 1] = wp4[(18 + j) * 8 + 1];
    }
    // compute steps 12..17 from A
#pragma unroll
    for (int kk = 0; kk < 6; ++kk) MSTEP(12 + kk, wa[2 * kk], wa[2 * kk + 1]);
    // compute steps 18..23 from B
#pragma unroll
    for (int kk = 0; kk < 6; ++kk) MSTEP(18 + kk, wb[2 * kk], wb[2 * kk + 1]);

    // C[row=b][col=v]: row = (lane>>4)*4 + reg, col = lane&15  (m89-verified)
    if (vl < len) {
        float* rp = res + start + vl;
#pragma unroll
        for (int r2 = 0; r2 < 4; ++r2) {
            rp[(size_t)(kq * 4 + r2) * SB]      = acc0[r2];
            rp[(size_t)(16 + kq * 4 + r2) * SB] = acc1[r2];
        }
    }
}

// ---------- combine: gather 1 res plane via posOf, coalesced out writes ------
__global__ void combine_k(const float* __restrict__ res, const int* __restrict__ posOf,
                          const float* __restrict__ bias, float* __restrict__ out) {
    const int v = blockIdx.x * 256 + threadIdx.x;
    if (v >= VV) return;
    const int b = blockIdx.y;
    const int pos = posOf[v];
    out[(size_t)b * VV + v] = res[(size_t)b * SB + pos] + bias[v];
}

extern "C" void kernel_launch(void* const* d_in, const int* in_sizes, int n_in,
                              void* d_out, int out_size, void* d_ws, size_t ws_size,
                              hipStream_t stream) {
    const float* OT   = (const float*)d_in[0];  // [B,Q,H]
    const float* W    = (const float*)d_in[1];  // [V,H]
    const float* bias = (const float*)d_in[2];  // [V]
    const int*   pid  = (const int*)d_in[3];    // [V]
    float* out = (float*)d_out;                 // [B,V]

    char* ws = (char*)d_ws;
    int*   h      = (int*)(ws + WS_H);
    int*   ntot   = (int*)(ws + WS_NTOT);
    int4*  desc   = (int4*)(ws + WS_DESC);
    int*   sorted = (int*)(ws + WS_SORTED);
    int*   posOf  = (int*)(ws + WS_POSOF);
    float* res    = (float*)(ws + WS_RES);

    hist_k<<<NB, 256, 0, stream>>>(pid, h);
    scat_k<<<NB, 256, 0, stream>>>(pid, h, sorted, posOf, desc, ntot);

    main_k<<<MAXDESC, 256, 0, stream>>>(OT, W, sorted, desc, ntot, res);

    combine_k<<<dim3((VV + 255) / 256, BB), 256, 0, stream>>>(res, posOf, bias, out);
}